// Round 2
// baseline (692.601 us; speedup 1.0000x reference)
//
#include <hip/hip_runtime.h>
#include <hip/hip_bf16.h>
#include <math.h>

// Problem constants
#define B_    8
#define S_    2048
#define KIN_  512
#define NIN_  4096
#define P_    2048
#define D_    1024
#define KSEL_ 256

// ---------------------------------------------------------------------------
// Kernel 1: gather per-batch combination weights
// Gw[b][p][j] = W[p][idx[b][j]]   (idx is int32 per harness contract)
// ---------------------------------------------------------------------------
__global__ void gather_w_kernel(const float* __restrict__ W,
                                const int* __restrict__ idx,
                                float* __restrict__ Gw) {
    int bp = blockIdx.x;            // 0 .. B*P-1
    int b  = bp >> 11;              // / 2048
    const int* ib = idx + (size_t)b * KIN_;
    const float* wrow = W + (size_t)(bp & 2047) * NIN_;
    float* grow = Gw + (size_t)bp * KIN_;
    for (int j = threadIdx.x; j < KIN_; j += 256) {
        grow[j] = wrow[ib[j]];
    }
}

// ---------------------------------------------------------------------------
// Kernel 2: per-batch NT GEMM  x[s,p] = sum_j A[s,j]*Gw[p,j], exact GELU,
// bf16 store of process_act, fused per-column score partial sums.
// Tile 128x128, BK=16, 256 threads, 8x8 microtile.
// ---------------------------------------------------------------------------
__global__ __launch_bounds__(256) void gemm1_kernel(
        const float* __restrict__ A, const float* __restrict__ Gw,
        __hip_bfloat16* __restrict__ C, float* __restrict__ scores) {
    __shared__ float As[16][132];
    __shared__ float Bs[16][132];
    __shared__ float red[16][128];

    int b  = blockIdx.z;
    int s0 = blockIdx.y * 128;
    int p0 = blockIdx.x * 128;
    const float* Ab = A  + (size_t)b * S_ * KIN_;
    const float* Gb = Gw + (size_t)b * P_ * KIN_;

    int t  = threadIdx.x;
    int tx = t & 15, ty = t >> 4;

    float acc[8][8];
#pragma unroll
    for (int i = 0; i < 8; i++)
#pragma unroll
        for (int j = 0; j < 8; j++) acc[i][j] = 0.0f;

    for (int k0 = 0; k0 < KIN_; k0 += 16) {
#pragma unroll
        for (int i = 0; i < 2; i++) {
            int f  = t + i * 256;
            int r  = f >> 2;
            int jj = (f & 3) << 2;
            float4 va = *reinterpret_cast<const float4*>(
                Ab + (size_t)(s0 + r) * KIN_ + k0 + jj);
            As[jj + 0][r] = va.x; As[jj + 1][r] = va.y;
            As[jj + 2][r] = va.z; As[jj + 3][r] = va.w;
            float4 vb = *reinterpret_cast<const float4*>(
                Gb + (size_t)(p0 + r) * KIN_ + k0 + jj);
            Bs[jj + 0][r] = vb.x; Bs[jj + 1][r] = vb.y;
            Bs[jj + 2][r] = vb.z; Bs[jj + 3][r] = vb.w;
        }
        __syncthreads();
#pragma unroll
        for (int kk = 0; kk < 16; kk++) {
            float4 a0 = *reinterpret_cast<const float4*>(&As[kk][ty * 8]);
            float4 a1 = *reinterpret_cast<const float4*>(&As[kk][ty * 8 + 4]);
            float4 b0 = *reinterpret_cast<const float4*>(&Bs[kk][tx * 8]);
            float4 b1 = *reinterpret_cast<const float4*>(&Bs[kk][tx * 8 + 4]);
            float av[8] = {a0.x, a0.y, a0.z, a0.w, a1.x, a1.y, a1.z, a1.w};
            float bv[8] = {b0.x, b0.y, b0.z, b0.w, b1.x, b1.y, b1.z, b1.w};
#pragma unroll
            for (int i = 0; i < 8; i++)
#pragma unroll
                for (int j = 0; j < 8; j++)
                    acc[i][j] = fmaf(av[i], bv[j], acc[i][j]);
        }
        __syncthreads();
    }

    // Epilogue: exact GELU, bf16 store, per-column partial sums
    float colsum[8];
#pragma unroll
    for (int j = 0; j < 8; j++) colsum[j] = 0.0f;
#pragma unroll
    for (int i = 0; i < 8; i++) {
        union { __hip_bfloat16 h[8]; uint4 u4; } row;
#pragma unroll
        for (int j = 0; j < 8; j++) {
            float x = acc[i][j];
            float g = 0.5f * x * (1.0f + erff(x * 0.70710678118654752f));
            colsum[j] += g;
            row.h[j] = __float2bfloat16(g);
        }
        *reinterpret_cast<uint4*>(
            C + ((size_t)b * S_ + s0 + ty * 8 + i) * P_ + p0 + tx * 8) = row.u4;
    }
#pragma unroll
    for (int j = 0; j < 8; j++) red[ty][tx * 8 + j] = colsum[j];
    __syncthreads();
    if (ty == 0) {
#pragma unroll
        for (int j = 0; j < 8; j++) {
            int col = tx * 8 + j;
            float s = 0.0f;
#pragma unroll
            for (int yy = 0; yy < 16; yy++) s += red[yy][col];
            atomicAdd(&scores[b * P_ + p0 + col], s);
        }
    }
}

// ---------------------------------------------------------------------------
// Kernel 3: per-batch top-256 of 2048 scores via bitonic sort (desc, tie: low idx)
// ---------------------------------------------------------------------------
__global__ __launch_bounds__(1024) void topk_kernel(const float* __restrict__ scores,
                                                    int* __restrict__ pidx) {
    __shared__ float v[2048];
    __shared__ int   ix[2048];
    int b = blockIdx.x;
    int t = threadIdx.x;
    for (int i = t; i < 2048; i += 1024) { v[i] = scores[b * 2048 + i]; ix[i] = i; }
    __syncthreads();
    for (int k = 2; k <= 2048; k <<= 1) {
        for (int j = k >> 1; j > 0; j >>= 1) {
            for (int i = t; i < 2048; i += 1024) {
                int o = i ^ j;
                if (o > i) {
                    bool desc = ((i & k) == 0);
                    float va = v[i], vb = v[o];
                    int ia = ix[i], ib = ix[o];
                    bool b_first = (vb > va) || (vb == va && ib < ia);
                    if (desc == b_first) {
                        v[i] = vb; v[o] = va; ix[i] = ib; ix[o] = ia;
                    }
                }
            }
            __syncthreads();
        }
    }
    if (t < KSEL_) pidx[b * KSEL_ + t] = ix[t];
}

// ---------------------------------------------------------------------------
// Kernel 4: gather selected activation columns: selact[b][s][t] = C[b][s][pidx[b][t]]
// ---------------------------------------------------------------------------
__global__ void gather_act_kernel(const unsigned short* __restrict__ C,
                                  const int* __restrict__ pidx,
                                  unsigned short* __restrict__ selact) {
    int s = blockIdx.x;
    int b = blockIdx.y;
    int t = threadIdx.x;   // 256
    int pi = pidx[b * KSEL_ + t];
    selact[((size_t)b * S_ + s) * KSEL_ + t] = C[((size_t)b * S_ + s) * P_ + pi];
}

// ---------------------------------------------------------------------------
// Kernel 5: per-batch NN GEMM: out[s,d] = sum_t selact[s,t] * proj[pidx[t]][d]
// A bf16 [S x 256], B rows indirect fp32. Tile 128x128, BK=16, 8x8 microtile.
// ---------------------------------------------------------------------------
__global__ __launch_bounds__(256) void gemm2_kernel(
        const unsigned short* __restrict__ Aact, const float* __restrict__ proj,
        const int* __restrict__ pidx, float* __restrict__ out) {
    __shared__ float As[16][132];
    __shared__ float Bs[16][132];

    int b  = blockIdx.z;
    int s0 = blockIdx.y * 128;
    int n0 = blockIdx.x * 128;
    const unsigned short* Ab = Aact + (size_t)b * S_ * KSEL_;
    const int* pb = pidx + b * KSEL_;

    int t  = threadIdx.x;
    int tx = t & 15, ty = t >> 4;

    float acc[8][8];
#pragma unroll
    for (int i = 0; i < 8; i++)
#pragma unroll
        for (int j = 0; j < 8; j++) acc[i][j] = 0.0f;

    for (int k0 = 0; k0 < KSEL_; k0 += 16) {
        {   // A tile: 128 rows x 16 bf16, one 16B load (8 bf16) per thread
            int r  = t >> 1;
            int jj = (t & 1) << 3;
            uint4 u = *reinterpret_cast<const uint4*>(
                Ab + (size_t)(s0 + r) * KSEL_ + k0 + jj);
            As[jj + 0][r] = __uint_as_float(u.x << 16);
            As[jj + 1][r] = __uint_as_float(u.x & 0xffff0000u);
            As[jj + 2][r] = __uint_as_float(u.y << 16);
            As[jj + 3][r] = __uint_as_float(u.y & 0xffff0000u);
            As[jj + 4][r] = __uint_as_float(u.z << 16);
            As[jj + 5][r] = __uint_as_float(u.z & 0xffff0000u);
            As[jj + 6][r] = __uint_as_float(u.w << 16);
            As[jj + 7][r] = __uint_as_float(u.w & 0xffff0000u);
        }
#pragma unroll
        for (int i = 0; i < 2; i++) {   // B tile: 16 rows x 128 fp32, indirect rows
            int f  = t + i * 256;
            int kk = f >> 5;
            int n4 = (f & 31) << 2;
            int row = pb[k0 + kk];
            float4 v = *reinterpret_cast<const float4*>(
                proj + (size_t)row * D_ + n0 + n4);
            *reinterpret_cast<float4*>(&Bs[kk][n4]) = v;
        }
        __syncthreads();
#pragma unroll
        for (int kk = 0; kk < 16; kk++) {
            float4 a0 = *reinterpret_cast<const float4*>(&As[kk][ty * 8]);
            float4 a1 = *reinterpret_cast<const float4*>(&As[kk][ty * 8 + 4]);
            float4 b0 = *reinterpret_cast<const float4*>(&Bs[kk][tx * 8]);
            float4 b1 = *reinterpret_cast<const float4*>(&Bs[kk][tx * 8 + 4]);
            float av[8] = {a0.x, a0.y, a0.z, a0.w, a1.x, a1.y, a1.z, a1.w};
            float bv[8] = {b0.x, b0.y, b0.z, b0.w, b1.x, b1.y, b1.z, b1.w};
#pragma unroll
            for (int i = 0; i < 8; i++)
#pragma unroll
                for (int j = 0; j < 8; j++)
                    acc[i][j] = fmaf(av[i], bv[j], acc[i][j]);
        }
        __syncthreads();
    }

#pragma unroll
    for (int i = 0; i < 8; i++) {
        float* orow = out + ((size_t)b * S_ + s0 + ty * 8 + i) * D_ + n0 + tx * 8;
        *reinterpret_cast<float4*>(orow) =
            make_float4(acc[i][0], acc[i][1], acc[i][2], acc[i][3]);
        *reinterpret_cast<float4*>(orow + 4) =
            make_float4(acc[i][4], acc[i][5], acc[i][6], acc[i][7]);
    }
}

// ---------------------------------------------------------------------------
// Workspace layout (bytes):
//   Gw     fp32 [8][2048][512]   @ 0          (33,554,432)
//   Cbf    bf16 [8][2048][2048]  @ 33,554,432 (67,108,864)
//   scores fp32 [8][2048]        @ 100,663,296 (65,536)
//   pidx   int  [8][256]         @ 100,728,832 (8,192)
//   selact bf16 [8][2048][256]   @ 100,737,024 (8,388,608)
//   total: 109,125,632 bytes
// ---------------------------------------------------------------------------
extern "C" void kernel_launch(void* const* d_in, const int* in_sizes, int n_in,
                              void* d_out, int out_size, void* d_ws, size_t ws_size,
                              hipStream_t stream) {
    (void)in_sizes; (void)n_in; (void)out_size; (void)ws_size;
    const float* act  = (const float*)d_in[0];
    const int*   idx  = (const int*)d_in[1];     // harness: integer -> const int*
    const float* W    = (const float*)d_in[3];
    const float* proj = (const float*)d_in[4];
    float*       out  = (float*)d_out;

    char* ws = (char*)d_ws;
    float*           Gw     = (float*)(ws + 0);
    __hip_bfloat16*  Cbf    = (__hip_bfloat16*)(ws + 33554432);
    float*           scores = (float*)(ws + 100663296);
    int*             pidx   = (int*)(ws + 100728832);
    unsigned short*  selact = (unsigned short*)(ws + 100737024);

    hipMemsetAsync(scores, 0, B_ * P_ * sizeof(float), stream);

    gather_w_kernel<<<dim3(B_ * P_), 256, 0, stream>>>(W, idx, Gw);
    gemm1_kernel<<<dim3(P_ / 128, S_ / 128, B_), 256, 0, stream>>>(act, Gw, Cbf, scores);
    topk_kernel<<<dim3(B_), 1024, 0, stream>>>(scores, pidx);
    gather_act_kernel<<<dim3(S_, B_), 256, 0, stream>>>(
        (const unsigned short*)Cbf, pidx, (unsigned short*)selact);
    gemm2_kernel<<<dim3(D_ / 128, S_ / 128, B_), 256, 0, stream>>>(
        (const unsigned short*)selact, proj, pidx, out);
}

// Round 3
// 481.338 us; speedup vs baseline: 1.4389x; 1.4389x over previous
//
#include <hip/hip_runtime.h>
#include <hip/hip_bf16.h>
#include <math.h>

#define B_    8
#define S_    2048
#define KIN_  512
#define NIN_  4096
#define P_    2048
#define D_    1024
#define KSEL_ 256

typedef __attribute__((ext_vector_type(8))) short short8;
typedef __attribute__((ext_vector_type(4))) float f32x4;

__device__ __forceinline__ unsigned short f2bf(float f) {
    unsigned u = __float_as_uint(f);
    unsigned r = (u + 0x7fffu + ((u >> 16) & 1u)) >> 16;
    return (unsigned short)r;
}
__device__ __forceinline__ float bf2f(unsigned short h) {
    return __uint_as_float(((unsigned)h) << 16);
}
__device__ __forceinline__ float gelu_exact(float x) {
    return 0.5f * x * (1.0f + erff(x * 0.70710678118654752f));
}
__device__ __forceinline__ void gl2lds16(const void* g, void* l) {
    __builtin_amdgcn_global_load_lds(
        (const __attribute__((address_space(1))) unsigned int*)g,
        (__attribute__((address_space(3))) unsigned int*)l, 16, 0, 0);
}

// ---------------------------------------------------------------------------
// Split A fp32 -> Ahi/Alo bf16
// ---------------------------------------------------------------------------
__global__ void split_a_kernel(const float* __restrict__ A,
                               unsigned short* __restrict__ Ahi,
                               unsigned short* __restrict__ Alo) {
    size_t i = (size_t)blockIdx.x * 256 + threadIdx.x;   // float4 index
    float4 v = reinterpret_cast<const float4*>(A)[i];
    ushort4 hi, lo;
    hi.x = f2bf(v.x); lo.x = f2bf(v.x - bf2f(hi.x));
    hi.y = f2bf(v.y); lo.y = f2bf(v.y - bf2f(hi.y));
    hi.z = f2bf(v.z); lo.z = f2bf(v.z - bf2f(hi.z));
    hi.w = f2bf(v.w); lo.w = f2bf(v.w - bf2f(hi.w));
    reinterpret_cast<ushort4*>(Ahi)[i] = hi;
    reinterpret_cast<ushort4*>(Alo)[i] = lo;
}

// ---------------------------------------------------------------------------
// Gather per-batch combination weights, split to bf16 hi/lo
// Ghi/Glo[b][p][j] = split(W[p][idx[b][j]])
// ---------------------------------------------------------------------------
__global__ void gather_w_kernel(const float* __restrict__ W,
                                const int* __restrict__ idx,
                                unsigned short* __restrict__ Ghi,
                                unsigned short* __restrict__ Glo) {
    int bp = blockIdx.x;            // 0 .. B*P-1
    int b  = bp >> 11;
    const int* ib = idx + (size_t)b * KIN_;
    const float* wrow = W + (size_t)(bp & 2047) * NIN_;
    size_t o = (size_t)bp * KIN_;
    for (int j = threadIdx.x; j < KIN_; j += 256) {
        float v = wrow[ib[j]];
        unsigned short h = f2bf(v);
        Ghi[o + j] = h;
        Glo[o + j] = f2bf(v - bf2f(h));
    }
}

// ---------------------------------------------------------------------------
// gemm1_score: x = A*G^T (3-term split bf16 MFMA), scores += sum_s gelu(x)
// 128x128 tile, BK=32, 4 waves, 4x4 16x16 acc tiles per wave. No C store.
// ---------------------------------------------------------------------------
__global__ __launch_bounds__(256) void gemm1_score(
        const unsigned short* __restrict__ Ahi, const unsigned short* __restrict__ Alo,
        const unsigned short* __restrict__ Ghi, const unsigned short* __restrict__ Glo,
        float* __restrict__ scores) {
    __shared__ unsigned short lds[16384];   // 4 tiles x [128][32] bf16 = 32 KB

    const int t  = threadIdx.x;
    const int b  = blockIdx.z;
    const int s0 = blockIdx.y * 128;
    const int p0 = blockIdx.x * 128;
    const int w = t >> 6, l = t & 63;
    const int wm = w & 1, wn = w >> 1;
    const int lr = l & 15, quad = l >> 4;

    const int srow = t >> 2;
    const int koff = (t & 3) * 8;
    const size_t baseA = ((size_t)(b * S_ + s0)) * KIN_;
    const size_t baseG = ((size_t)(b * P_ + p0)) * KIN_;
    const size_t offA0 = baseA + (size_t)srow * KIN_ + koff;
    const size_t offA1 = offA0 + (size_t)64 * KIN_;
    const size_t offG0 = baseG + (size_t)srow * KIN_ + koff;
    const size_t offG1 = offG0 + (size_t)64 * KIN_;
    char* lb = (char*)lds + w * 1024;

    int ra[4], rg[4];
#pragma unroll
    for (int i = 0; i < 4; i++) {
        ra[i] = (wm * 64 + i * 16 + lr) * 32 + quad * 8;
        rg[i] = (wn * 64 + i * 16 + lr) * 32 + quad * 8;
    }

    f32x4 acc[4][4];
#pragma unroll
    for (int i = 0; i < 4; i++)
#pragma unroll
        for (int j = 0; j < 4; j++) acc[i][j] = (f32x4){0.f, 0.f, 0.f, 0.f};

    for (int k0 = 0; k0 < KIN_; k0 += 32) {
        gl2lds16(Ahi + offA0 + k0, lb + 0);
        gl2lds16(Ahi + offA1 + k0, lb + 4096);
        gl2lds16(Alo + offA0 + k0, lb + 8192);
        gl2lds16(Alo + offA1 + k0, lb + 12288);
        gl2lds16(Ghi + offG0 + k0, lb + 16384);
        gl2lds16(Ghi + offG1 + k0, lb + 20480);
        gl2lds16(Glo + offG0 + k0, lb + 24576);
        gl2lds16(Glo + offG1 + k0, lb + 28672);
        __syncthreads();

        short8 ah[4], al8[4], gh[4], gl8[4];
#pragma unroll
        for (int i = 0; i < 4; i++) {
            ah[i]  = *(const short8*)(lds + ra[i]);
            al8[i] = *(const short8*)(lds + 4096 + ra[i]);
            gh[i]  = *(const short8*)(lds + 8192 + rg[i]);
            gl8[i] = *(const short8*)(lds + 12288 + rg[i]);
        }
#pragma unroll
        for (int mt = 0; mt < 4; mt++)
#pragma unroll
            for (int nt = 0; nt < 4; nt++) {
                acc[mt][nt] = __builtin_amdgcn_mfma_f32_16x16x32_bf16(ah[mt],  gh[nt],  acc[mt][nt], 0, 0, 0);
                acc[mt][nt] = __builtin_amdgcn_mfma_f32_16x16x32_bf16(ah[mt],  gl8[nt], acc[mt][nt], 0, 0, 0);
                acc[mt][nt] = __builtin_amdgcn_mfma_f32_16x16x32_bf16(al8[mt], gh[nt],  acc[mt][nt], 0, 0, 0);
            }
        __syncthreads();
    }

    // Epilogue: gelu + per-column sums (column = p, summed over this wave's 64 s rows)
    float colsum[4] = {0.f, 0.f, 0.f, 0.f};
#pragma unroll
    for (int mt = 0; mt < 4; mt++)
#pragma unroll
        for (int nt = 0; nt < 4; nt++)
#pragma unroll
            for (int r = 0; r < 4; r++)
                colsum[nt] += gelu_exact(acc[mt][nt][r]);
#pragma unroll
    for (int nt = 0; nt < 4; nt++) {
        colsum[nt] += __shfl_xor(colsum[nt], 16);
        colsum[nt] += __shfl_xor(colsum[nt], 32);
    }
    if (quad == 0) {
#pragma unroll
        for (int nt = 0; nt < 4; nt++)
            atomicAdd(&scores[b * P_ + p0 + wn * 64 + nt * 16 + lr], colsum[nt]);
    }
}

// ---------------------------------------------------------------------------
// top-256 of 2048 scores per batch (bitonic, desc, tie: low idx)
// ---------------------------------------------------------------------------
__global__ __launch_bounds__(1024) void topk_kernel(const float* __restrict__ scores,
                                                    int* __restrict__ pidx) {
    __shared__ float v[2048];
    __shared__ int   ix[2048];
    int b = blockIdx.x;
    int t = threadIdx.x;
    for (int i = t; i < 2048; i += 1024) { v[i] = scores[b * 2048 + i]; ix[i] = i; }
    __syncthreads();
    for (int k = 2; k <= 2048; k <<= 1) {
        for (int j = k >> 1; j > 0; j >>= 1) {
            for (int i = t; i < 2048; i += 1024) {
                int o = i ^ j;
                if (o > i) {
                    bool desc = ((i & k) == 0);
                    float va = v[i], vb = v[o];
                    int ia = ix[i], ib = ix[o];
                    bool b_first = (vb > va) || (vb == va && ib < ia);
                    if (desc == b_first) { v[i] = vb; v[o] = va; ix[i] = ib; ix[o] = ia; }
                }
            }
            __syncthreads();
        }
    }
    if (t < KSEL_) pidx[b * KSEL_ + t] = ix[t];
}

// ---------------------------------------------------------------------------
// gemm1b: recompute ONLY the selected 256 columns -> selact bf16 [b][s][256]
// Same 3-term split MFMA; G rows indirect via pidx. Epilogue: gelu + LDS
// transpose staging + coalesced uint4 stores.
// ---------------------------------------------------------------------------
__global__ __launch_bounds__(256) void gemm1b_selact(
        const unsigned short* __restrict__ Ahi, const unsigned short* __restrict__ Alo,
        const unsigned short* __restrict__ Ghi, const unsigned short* __restrict__ Glo,
        const int* __restrict__ pidx, unsigned short* __restrict__ selact) {
    __shared__ unsigned short lds[16384];

    const int t  = threadIdx.x;
    const int b  = blockIdx.z;
    const int s0 = blockIdx.y * 128;
    const int n0 = blockIdx.x * 128;   // selected-column tile
    const int w = t >> 6, l = t & 63;
    const int wm = w & 1, wn = w >> 1;
    const int lr = l & 15, quad = l >> 4;

    const int srow = t >> 2;
    const int koff = (t & 3) * 8;
    const size_t baseA = ((size_t)(b * S_ + s0)) * KIN_;
    const size_t offA0 = baseA + (size_t)srow * KIN_ + koff;
    const size_t offA1 = offA0 + (size_t)64 * KIN_;
    const int prow0 = pidx[b * KSEL_ + n0 + srow];
    const int prow1 = pidx[b * KSEL_ + n0 + 64 + srow];
    const size_t offG0 = ((size_t)(b * P_ + prow0)) * KIN_ + koff;
    const size_t offG1 = ((size_t)(b * P_ + prow1)) * KIN_ + koff;
    char* lb = (char*)lds + w * 1024;

    int ra[4], rg[4];
#pragma unroll
    for (int i = 0; i < 4; i++) {
        ra[i] = (wm * 64 + i * 16 + lr) * 32 + quad * 8;
        rg[i] = (wn * 64 + i * 16 + lr) * 32 + quad * 8;
    }

    f32x4 acc[4][4];
#pragma unroll
    for (int i = 0; i < 4; i++)
#pragma unroll
        for (int j = 0; j < 4; j++) acc[i][j] = (f32x4){0.f, 0.f, 0.f, 0.f};

    for (int k0 = 0; k0 < KIN_; k0 += 32) {
        gl2lds16(Ahi + offA0 + k0, lb + 0);
        gl2lds16(Ahi + offA1 + k0, lb + 4096);
        gl2lds16(Alo + offA0 + k0, lb + 8192);
        gl2lds16(Alo + offA1 + k0, lb + 12288);
        gl2lds16(Ghi + offG0 + k0, lb + 16384);
        gl2lds16(Ghi + offG1 + k0, lb + 20480);
        gl2lds16(Glo + offG0 + k0, lb + 24576);
        gl2lds16(Glo + offG1 + k0, lb + 28672);
        __syncthreads();

        short8 ah[4], al8[4], gh[4], gl8[4];
#pragma unroll
        for (int i = 0; i < 4; i++) {
            ah[i]  = *(const short8*)(lds + ra[i]);
            al8[i] = *(const short8*)(lds + 4096 + ra[i]);
            gh[i]  = *(const short8*)(lds + 8192 + rg[i]);
            gl8[i] = *(const short8*)(lds + 12288 + rg[i]);
        }
#pragma unroll
        for (int mt = 0; mt < 4; mt++)
#pragma unroll
            for (int nt = 0; nt < 4; nt++) {
                acc[mt][nt] = __builtin_amdgcn_mfma_f32_16x16x32_bf16(ah[mt],  gh[nt],  acc[mt][nt], 0, 0, 0);
                acc[mt][nt] = __builtin_amdgcn_mfma_f32_16x16x32_bf16(ah[mt],  gl8[nt], acc[mt][nt], 0, 0, 0);
                acc[mt][nt] = __builtin_amdgcn_mfma_f32_16x16x32_bf16(al8[mt], gh[nt],  acc[mt][nt], 0, 0, 0);
            }
        __syncthreads();
    }

    // Epilogue: gelu -> bf16 C tile in LDS -> coalesced stores
#pragma unroll
    for (int mt = 0; mt < 4; mt++)
#pragma unroll
        for (int nt = 0; nt < 4; nt++)
#pragma unroll
            for (int r = 0; r < 4; r++) {
                int row = wm * 64 + mt * 16 + quad * 4 + r;
                int col = wn * 64 + nt * 16 + lr;
                lds[row * 128 + col] = f2bf(gelu_exact(acc[mt][nt][r]));
            }
    __syncthreads();
    for (int i = t; i < 2048; i += 256) {
        int row = i >> 4, ch = i & 15;
        uint4 v = *(const uint4*)(lds + row * 128 + ch * 8);
        *(uint4*)(selact + ((size_t)(b * S_ + s0 + row)) * KSEL_ + n0 + ch * 8) = v;
    }
}

// ---------------------------------------------------------------------------
// Transposed bf16 selected projections: PselT[b][d][k] = bf16(proj[pidx[b][k]][d])
// 64x64 LDS-tiled transpose, coalesced both sides.
// ---------------------------------------------------------------------------
__global__ void gather_proj_t(const float* __restrict__ proj,
                              const int* __restrict__ pidx,
                              unsigned short* __restrict__ PselT) {
    __shared__ unsigned short tile[64][65];
    int d0 = blockIdx.x * 64, k0 = blockIdx.y * 64, b = blockIdx.z;
    int tr = threadIdx.x >> 6;     // 0..3
    int tc = threadIdx.x & 63;
#pragma unroll
    for (int r = 0; r < 16; r++) {
        int kk = r * 4 + tr;
        int prow = pidx[b * KSEL_ + k0 + kk];
        tile[kk][tc] = f2bf(proj[(size_t)prow * D_ + d0 + tc]);
    }
    __syncthreads();
#pragma unroll
    for (int r = 0; r < 16; r++) {
        int dd = r * 4 + tr;
        PselT[((size_t)(b * D_ + d0 + dd)) * KSEL_ + k0 + tc] = tile[tc][dd];
    }
}

// ---------------------------------------------------------------------------
// gemm2: out[b][s][d] = sum_k selact[b][s][k] * PselT[b][d][k]  (bf16 MFMA)
// ---------------------------------------------------------------------------
__global__ __launch_bounds__(256) void gemm2_mfma(
        const unsigned short* __restrict__ selact,
        const unsigned short* __restrict__ PselT,
        float* __restrict__ out) {
    __shared__ unsigned short lds[8192];   // 2 tiles x [128][32]

    const int t  = threadIdx.x;
    const int b  = blockIdx.z;
    const int s0 = blockIdx.y * 128;
    const int d0 = blockIdx.x * 128;
    const int w = t >> 6, l = t & 63;
    const int wm = w & 1, wn = w >> 1;
    const int lr = l & 15, quad = l >> 4;

    const int srow = t >> 2;
    const int koff = (t & 3) * 8;
    const size_t offA0 = ((size_t)(b * S_ + s0 + srow)) * KSEL_ + koff;
    const size_t offA1 = offA0 + (size_t)64 * KSEL_;
    const size_t offB0 = ((size_t)(b * D_ + d0 + srow)) * KSEL_ + koff;
    const size_t offB1 = offB0 + (size_t)64 * KSEL_;
    char* lb = (char*)lds + w * 1024;

    int ra[4], rg[4];
#pragma unroll
    for (int i = 0; i < 4; i++) {
        ra[i] = (wm * 64 + i * 16 + lr) * 32 + quad * 8;
        rg[i] = (wn * 64 + i * 16 + lr) * 32 + quad * 8;
    }

    f32x4 acc[4][4];
#pragma unroll
    for (int i = 0; i < 4; i++)
#pragma unroll
        for (int j = 0; j < 4; j++) acc[i][j] = (f32x4){0.f, 0.f, 0.f, 0.f};

    for (int k0 = 0; k0 < KSEL_; k0 += 32) {
        gl2lds16(selact + offA0 + k0, lb + 0);
        gl2lds16(selact + offA1 + k0, lb + 4096);
        gl2lds16(PselT  + offB0 + k0, lb + 8192);
        gl2lds16(PselT  + offB1 + k0, lb + 12288);
        __syncthreads();

        short8 af[4], bf[4];
#pragma unroll
        for (int i = 0; i < 4; i++) {
            af[i] = *(const short8*)(lds + ra[i]);
            bf[i] = *(const short8*)(lds + 4096 + rg[i]);
        }
#pragma unroll
        for (int mt = 0; mt < 4; mt++)
#pragma unroll
            for (int nt = 0; nt < 4; nt++)
                acc[mt][nt] = __builtin_amdgcn_mfma_f32_16x16x32_bf16(af[mt], bf[nt], acc[mt][nt], 0, 0, 0);
        __syncthreads();
    }

#pragma unroll
    for (int mt = 0; mt < 4; mt++)
#pragma unroll
        for (int nt = 0; nt < 4; nt++)
#pragma unroll
            for (int r = 0; r < 4; r++)
                out[((size_t)(b * S_ + s0 + wm * 64 + mt * 16 + quad * 4 + r)) * D_
                    + d0 + wn * 64 + nt * 16 + lr] = acc[mt][nt][r];
}

// ---------------------------------------------------------------------------
// Workspace layout (bytes):
//   Ahi    bf16 [8][2048][512] @ 0           (16,777,216)
//   Alo    bf16 [8][2048][512] @ 16,777,216  (16,777,216)
//   Ghi    bf16 [8][2048][512] @ 33,554,432  (16,777,216)
//   Glo    bf16 [8][2048][512] @ 50,331,648  (16,777,216)
//   scores fp32 [8][2048]      @ 67,108,864  (65,536)
//   pidx   int  [8][256]       @ 67,174,400  (8,192)
//   selact bf16 [8][2048][256] @ 67,182,592  (8,388,608)
//   PselT  bf16 [8][1024][256] @ 75,571,200  (4,194,304)
//   total: 79,765,504 bytes
// ---------------------------------------------------------------------------
extern "C" void kernel_launch(void* const* d_in, const int* in_sizes, int n_in,
                              void* d_out, int out_size, void* d_ws, size_t ws_size,
                              hipStream_t stream) {
    (void)in_sizes; (void)n_in; (void)out_size; (void)ws_size;
    const float* act  = (const float*)d_in[0];
    const int*   idx  = (const int*)d_in[1];
    const float* W    = (const float*)d_in[3];
    const float* proj = (const float*)d_in[4];
    float*       out  = (float*)d_out;

    char* ws = (char*)d_ws;
    unsigned short* Ahi    = (unsigned short*)(ws + 0);
    unsigned short* Alo    = (unsigned short*)(ws + 16777216);
    unsigned short* Ghi    = (unsigned short*)(ws + 33554432);
    unsigned short* Glo    = (unsigned short*)(ws + 50331648);
    float*          scores = (float*)(ws + 67108864);
    int*            pidx   = (int*)(ws + 67174400);
    unsigned short* selact = (unsigned short*)(ws + 67182592);
    unsigned short* PselT  = (unsigned short*)(ws + 75571200);

    hipMemsetAsync(scores, 0, B_ * P_ * sizeof(float), stream);

    split_a_kernel<<<dim3(B_ * S_ * KIN_ / 1024), 256, 0, stream>>>(act, Ahi, Alo);
    gather_w_kernel<<<dim3(B_ * P_), 256, 0, stream>>>(W, idx, Ghi, Glo);
    gemm1_score<<<dim3(P_ / 128, S_ / 128, B_), 256, 0, stream>>>(Ahi, Alo, Ghi, Glo, scores);
    topk_kernel<<<dim3(B_), 1024, 0, stream>>>(scores, pidx);
    gemm1b_selact<<<dim3(KSEL_ / 128, S_ / 128, B_), 256, 0, stream>>>(
        Ahi, Alo, Ghi, Glo, pidx, selact);
    gather_proj_t<<<dim3(D_ / 64, KSEL_ / 64, B_), 256, 0, stream>>>(proj, pidx, PselT);
    gemm2_mfma<<<dim3(D_ / 128, S_ / 128, B_), 256, 0, stream>>>(selact, PselT, out);
}

// Round 4
// 415.004 us; speedup vs baseline: 1.6689x; 1.1598x over previous
//
#include <hip/hip_runtime.h>
#include <hip/hip_bf16.h>
#include <math.h>

#define B_    8
#define S_    2048
#define KIN_  512
#define NIN_  4096
#define P_    2048
#define D_    1024
#define KSEL_ 256

typedef __attribute__((ext_vector_type(8))) short short8;
typedef __attribute__((ext_vector_type(4))) float f32x4;

__device__ __forceinline__ unsigned short f2bf(float f) {
    unsigned u = __float_as_uint(f);
    unsigned r = (u + 0x7fffu + ((u >> 16) & 1u)) >> 16;
    return (unsigned short)r;
}
__device__ __forceinline__ float bf2f(unsigned short h) {
    return __uint_as_float(((unsigned)h) << 16);
}
__device__ __forceinline__ float gelu_exact(float x) {
    return 0.5f * x * (1.0f + erff(x * 0.70710678118654752f));
}
__device__ __forceinline__ void gl2lds16(const void* g, void* l) {
    __builtin_amdgcn_global_load_lds(
        (const __attribute__((address_space(1))) unsigned int*)g,
        (__attribute__((address_space(3))) unsigned int*)l, 16, 0, 0);
}

// ---------------------------------------------------------------------------
// Split A fp32 -> Ahi/Alo bf16
// ---------------------------------------------------------------------------
__global__ void split_a_kernel(const float* __restrict__ A,
                               unsigned short* __restrict__ Ahi,
                               unsigned short* __restrict__ Alo) {
    size_t i = (size_t)blockIdx.x * 256 + threadIdx.x;   // float4 index
    float4 v = reinterpret_cast<const float4*>(A)[i];
    ushort4 hi, lo;
    hi.x = f2bf(v.x); lo.x = f2bf(v.x - bf2f(hi.x));
    hi.y = f2bf(v.y); lo.y = f2bf(v.y - bf2f(hi.y));
    hi.z = f2bf(v.z); lo.z = f2bf(v.z - bf2f(hi.z));
    hi.w = f2bf(v.w); lo.w = f2bf(v.w - bf2f(hi.w));
    reinterpret_cast<ushort4*>(Ahi)[i] = hi;
    reinterpret_cast<ushort4*>(Alo)[i] = lo;
}

// ---------------------------------------------------------------------------
// Gather per-batch combination weights, split to bf16 hi/lo
// ---------------------------------------------------------------------------
__global__ void gather_w_kernel(const float* __restrict__ W,
                                const int* __restrict__ idx,
                                unsigned short* __restrict__ Ghi,
                                unsigned short* __restrict__ Glo) {
    int bp = blockIdx.x;            // 0 .. B*P-1
    int b  = bp >> 11;
    const int* ib = idx + (size_t)b * KIN_;
    const float* wrow = W + (size_t)(bp & 2047) * NIN_;
    size_t o = (size_t)bp * KIN_;
    for (int j = threadIdx.x; j < KIN_; j += 256) {
        float v = wrow[ib[j]];
        unsigned short h = f2bf(v);
        Ghi[o + j] = h;
        Glo[o + j] = f2bf(v - bf2f(h));
    }
}

// ---------------------------------------------------------------------------
// gemm1_score: x = A*G^T (3-term split bf16 MFMA), scores += sum_s gelu(x).
// Optionally (STORE_C) also writes bf16 gelu(x) to C [b][s][p].
// 128x128 tile, BK=32, double-buffered LDS staging with raw vmcnt/s_barrier:
// loads for iter k+1 are issued BEFORE waiting on iter k's (vmcnt(8)), so the
// pre-compute drain covers only loads issued a full iteration earlier.
// ---------------------------------------------------------------------------
template <bool STORE_C>
__global__ __launch_bounds__(256) void gemm1_score(
        const unsigned short* __restrict__ Ahi, const unsigned short* __restrict__ Alo,
        const unsigned short* __restrict__ Ghi, const unsigned short* __restrict__ Glo,
        float* __restrict__ scores, unsigned short* __restrict__ C) {
    __shared__ __align__(16) unsigned short lds[32768];  // 2 x 32KB buffers

    const int t  = threadIdx.x;
    const int b  = blockIdx.z;
    const int s0 = blockIdx.y * 128;
    const int p0 = blockIdx.x * 128;
    const int w = t >> 6, l = t & 63;
    const int wm = w & 1, wn = w >> 1;
    const int lr = l & 15, quad = l >> 4;

    const int srow = t >> 2;
    const int koff = (t & 3) * 8;
    const size_t baseA = ((size_t)(b * S_ + s0)) * KIN_;
    const size_t baseG = ((size_t)(b * P_ + p0)) * KIN_;
    const unsigned short* pA0 = Ahi + baseA + (size_t)srow * KIN_ + koff;
    const unsigned short* pA1 = pA0 + (size_t)64 * KIN_;
    const unsigned short* pL0 = Alo + baseA + (size_t)srow * KIN_ + koff;
    const unsigned short* pL1 = pL0 + (size_t)64 * KIN_;
    const unsigned short* pG0 = Ghi + baseG + (size_t)srow * KIN_ + koff;
    const unsigned short* pG1 = pG0 + (size_t)64 * KIN_;
    const unsigned short* pH0 = Glo + baseG + (size_t)srow * KIN_ + koff;
    const unsigned short* pH1 = pH0 + (size_t)64 * KIN_;
    char* lb = (char*)lds + w * 1024;

    int ra[4], rg[4];
#pragma unroll
    for (int i = 0; i < 4; i++) {
        ra[i] = (wm * 64 + i * 16 + lr) * 32 + quad * 8;
        rg[i] = (wn * 64 + i * 16 + lr) * 32 + quad * 8;
    }

    f32x4 acc[4][4];
#pragma unroll
    for (int i = 0; i < 4; i++)
#pragma unroll
        for (int j = 0; j < 4; j++) acc[i][j] = (f32x4){0.f, 0.f, 0.f, 0.f};

    auto issue = [&](int k0, int buf) {
        char* d = lb + buf * 32768;
        gl2lds16(pA0 + k0, d + 0);
        gl2lds16(pA1 + k0, d + 4096);
        gl2lds16(pL0 + k0, d + 8192);
        gl2lds16(pL1 + k0, d + 12288);
        gl2lds16(pG0 + k0, d + 16384);
        gl2lds16(pG1 + k0, d + 20480);
        gl2lds16(pH0 + k0, d + 24576);
        gl2lds16(pH1 + k0, d + 28672);
    };

    issue(0, 0);
    for (int it = 0; it < KIN_ / 32; ++it) {
        if (it + 1 < KIN_ / 32) {
            issue((it + 1) * 32, (it + 1) & 1);
            asm volatile("s_waitcnt vmcnt(8)\n\ts_barrier" ::: "memory");
        } else {
            asm volatile("s_waitcnt vmcnt(0)\n\ts_barrier" ::: "memory");
        }
        const unsigned short* Lb = lds + (it & 1) * 16384;

        short8 gh[4], gl8[4];
#pragma unroll
        for (int i = 0; i < 4; i++) {
            gh[i]  = *(const short8*)(Lb + 8192 + rg[i]);
            gl8[i] = *(const short8*)(Lb + 12288 + rg[i]);
        }
#pragma unroll
        for (int mt = 0; mt < 4; mt++) {
            short8 ah = *(const short8*)(Lb + ra[mt]);
            short8 al = *(const short8*)(Lb + 4096 + ra[mt]);
#pragma unroll
            for (int nt = 0; nt < 4; nt++) {
                acc[mt][nt] = __builtin_amdgcn_mfma_f32_16x16x32_bf16(ah, gh[nt],  acc[mt][nt], 0, 0, 0);
                acc[mt][nt] = __builtin_amdgcn_mfma_f32_16x16x32_bf16(ah, gl8[nt], acc[mt][nt], 0, 0, 0);
                acc[mt][nt] = __builtin_amdgcn_mfma_f32_16x16x32_bf16(al, gh[nt],  acc[mt][nt], 0, 0, 0);
            }
        }
        asm volatile("s_barrier" ::: "memory");
    }

    // Epilogue: gelu, per-column score sums, optional bf16 C tile store
    float colsum[4] = {0.f, 0.f, 0.f, 0.f};
#pragma unroll
    for (int mt = 0; mt < 4; mt++)
#pragma unroll
        for (int nt = 0; nt < 4; nt++)
#pragma unroll
            for (int r = 0; r < 4; r++) {
                float g = gelu_exact(acc[mt][nt][r]);
                colsum[nt] += g;
                acc[mt][nt][r] = g;
            }
#pragma unroll
    for (int nt = 0; nt < 4; nt++) {
        colsum[nt] += __shfl_xor(colsum[nt], 16);
        colsum[nt] += __shfl_xor(colsum[nt], 32);
    }
    if (quad == 0) {
#pragma unroll
        for (int nt = 0; nt < 4; nt++)
            atomicAdd(&scores[b * P_ + p0 + wn * 64 + nt * 16 + lr], colsum[nt]);
    }

    if (STORE_C) {
        // acc now holds gelu values; stage bf16 C tile in LDS, store coalesced
#pragma unroll
        for (int mt = 0; mt < 4; mt++)
#pragma unroll
            for (int nt = 0; nt < 4; nt++)
#pragma unroll
                for (int r = 0; r < 4; r++) {
                    int row = wm * 64 + mt * 16 + quad * 4 + r;
                    int col = wn * 64 + nt * 16 + lr;
                    lds[row * 128 + col] = f2bf(acc[mt][nt][r]);
                }
        __syncthreads();
        for (int i = t; i < 2048; i += 256) {
            int row = i >> 4, ch = i & 15;
            uint4 v = *(const uint4*)(lds + row * 128 + ch * 8);
            *(uint4*)(C + ((size_t)(b * S_ + s0 + row)) * P_ + p0 + ch * 8) = v;
        }
    }
}

// ---------------------------------------------------------------------------
// top-256 of 2048 scores per batch (bitonic, desc, tie: low idx)
// ---------------------------------------------------------------------------
__global__ __launch_bounds__(1024) void topk_kernel(const float* __restrict__ scores,
                                                    int* __restrict__ pidx) {
    __shared__ float v[2048];
    __shared__ int   ix[2048];
    int b = blockIdx.x;
    int t = threadIdx.x;
    for (int i = t; i < 2048; i += 1024) { v[i] = scores[b * 2048 + i]; ix[i] = i; }
    __syncthreads();
    for (int k = 2; k <= 2048; k <<= 1) {
        for (int j = k >> 1; j > 0; j >>= 1) {
            for (int i = t; i < 2048; i += 1024) {
                int o = i ^ j;
                if (o > i) {
                    bool desc = ((i & k) == 0);
                    float va = v[i], vb = v[o];
                    int ia = ix[i], ib = ix[o];
                    bool b_first = (vb > va) || (vb == va && ib < ia);
                    if (desc == b_first) { v[i] = vb; v[o] = va; ix[i] = ib; ix[o] = ia; }
                }
            }
            __syncthreads();
        }
    }
    if (t < KSEL_) pidx[b * KSEL_ + t] = ix[t];
}

// ---------------------------------------------------------------------------
// gather_act: selact[b][s][t] = C[b][s][pidx[b][t]]  (C-store path)
// ---------------------------------------------------------------------------
__global__ void gather_act_kernel(const unsigned short* __restrict__ C,
                                  const int* __restrict__ pidx,
                                  unsigned short* __restrict__ selact) {
    __shared__ int pj[256];
    int b = blockIdx.y, t = threadIdx.x;
    pj[t] = pidx[b * KSEL_ + t];
    __syncthreads();
    size_t r0 = (size_t)b * S_ + blockIdx.x * 8;
#pragma unroll
    for (int r = 0; r < 8; ++r) {
        size_t row = r0 + r;
        selact[row * KSEL_ + t] = C[row * P_ + pj[t]];
    }
}

// ---------------------------------------------------------------------------
// gemm1b (fallback when ws too small): recompute selected 256 columns
// ---------------------------------------------------------------------------
__global__ __launch_bounds__(256) void gemm1b_selact(
        const unsigned short* __restrict__ Ahi, const unsigned short* __restrict__ Alo,
        const unsigned short* __restrict__ Ghi, const unsigned short* __restrict__ Glo,
        const int* __restrict__ pidx, unsigned short* __restrict__ selact) {
    __shared__ __align__(16) unsigned short lds[16384];

    const int t  = threadIdx.x;
    const int b  = blockIdx.z;
    const int s0 = blockIdx.y * 128;
    const int n0 = blockIdx.x * 128;
    const int w = t >> 6, l = t & 63;
    const int wm = w & 1, wn = w >> 1;
    const int lr = l & 15, quad = l >> 4;

    const int srow = t >> 2;
    const int koff = (t & 3) * 8;
    const size_t baseA = ((size_t)(b * S_ + s0)) * KIN_;
    const size_t offA0 = baseA + (size_t)srow * KIN_ + koff;
    const size_t offA1 = offA0 + (size_t)64 * KIN_;
    const int prow0 = pidx[b * KSEL_ + n0 + srow];
    const int prow1 = pidx[b * KSEL_ + n0 + 64 + srow];
    const size_t offG0 = ((size_t)(b * P_ + prow0)) * KIN_ + koff;
    const size_t offG1 = ((size_t)(b * P_ + prow1)) * KIN_ + koff;
    char* lb = (char*)lds + w * 1024;

    int ra[4], rg[4];
#pragma unroll
    for (int i = 0; i < 4; i++) {
        ra[i] = (wm * 64 + i * 16 + lr) * 32 + quad * 8;
        rg[i] = (wn * 64 + i * 16 + lr) * 32 + quad * 8;
    }

    f32x4 acc[4][4];
#pragma unroll
    for (int i = 0; i < 4; i++)
#pragma unroll
        for (int j = 0; j < 4; j++) acc[i][j] = (f32x4){0.f, 0.f, 0.f, 0.f};

    for (int k0 = 0; k0 < KIN_; k0 += 32) {
        gl2lds16(Ahi + offA0 + k0, lb + 0);
        gl2lds16(Ahi + offA1 + k0, lb + 4096);
        gl2lds16(Alo + offA0 + k0, lb + 8192);
        gl2lds16(Alo + offA1 + k0, lb + 12288);
        gl2lds16(Ghi + offG0 + k0, lb + 16384);
        gl2lds16(Ghi + offG1 + k0, lb + 20480);
        gl2lds16(Glo + offG0 + k0, lb + 24576);
        gl2lds16(Glo + offG1 + k0, lb + 28672);
        __syncthreads();

        short8 ah[4], al8[4], gh[4], gl8[4];
#pragma unroll
        for (int i = 0; i < 4; i++) {
            ah[i]  = *(const short8*)(lds + ra[i]);
            al8[i] = *(const short8*)(lds + 4096 + ra[i]);
            gh[i]  = *(const short8*)(lds + 8192 + rg[i]);
            gl8[i] = *(const short8*)(lds + 12288 + rg[i]);
        }
#pragma unroll
        for (int mt = 0; mt < 4; mt++)
#pragma unroll
            for (int nt = 0; nt < 4; nt++) {
                acc[mt][nt] = __builtin_amdgcn_mfma_f32_16x16x32_bf16(ah[mt],  gh[nt],  acc[mt][nt], 0, 0, 0);
                acc[mt][nt] = __builtin_amdgcn_mfma_f32_16x16x32_bf16(ah[mt],  gl8[nt], acc[mt][nt], 0, 0, 0);
                acc[mt][nt] = __builtin_amdgcn_mfma_f32_16x16x32_bf16(al8[mt], gh[nt],  acc[mt][nt], 0, 0, 0);
            }
        __syncthreads();
    }

#pragma unroll
    for (int mt = 0; mt < 4; mt++)
#pragma unroll
        for (int nt = 0; nt < 4; nt++)
#pragma unroll
            for (int r = 0; r < 4; r++) {
                int row = wm * 64 + mt * 16 + quad * 4 + r;
                int col = wn * 64 + nt * 16 + lr;
                lds[row * 128 + col] = f2bf(gelu_exact(acc[mt][nt][r]));
            }
    __syncthreads();
    for (int i = t; i < 2048; i += 256) {
        int row = i >> 4, ch = i & 15;
        uint4 v = *(const uint4*)(lds + row * 128 + ch * 8);
        *(uint4*)(selact + ((size_t)(b * S_ + s0 + row)) * KSEL_ + n0 + ch * 8) = v;
    }
}

// ---------------------------------------------------------------------------
// Transposed bf16 selected projections: PselT[b][d][k] = bf16(proj[pidx[b][k]][d])
// ---------------------------------------------------------------------------
__global__ void gather_proj_t(const float* __restrict__ proj,
                              const int* __restrict__ pidx,
                              unsigned short* __restrict__ PselT) {
    __shared__ unsigned short tile[64][65];
    int d0 = blockIdx.x * 64, k0 = blockIdx.y * 64, b = blockIdx.z;
    int tr = threadIdx.x >> 6;     // 0..3
    int tc = threadIdx.x & 63;
#pragma unroll
    for (int r = 0; r < 16; r++) {
        int kk = r * 4 + tr;
        int prow = pidx[b * KSEL_ + k0 + kk];
        tile[kk][tc] = f2bf(proj[(size_t)prow * D_ + d0 + tc]);
    }
    __syncthreads();
#pragma unroll
    for (int r = 0; r < 16; r++) {
        int dd = r * 4 + tr;
        PselT[((size_t)(b * D_ + d0 + dd)) * KSEL_ + k0 + tc] = tile[tc][dd];
    }
}

// ---------------------------------------------------------------------------
// gemm2: out[b][s][d] = sum_k selact[b][s][k] * PselT[b][d][k]  (bf16 MFMA)
// ---------------------------------------------------------------------------
__global__ __launch_bounds__(256) void gemm2_mfma(
        const unsigned short* __restrict__ selact,
        const unsigned short* __restrict__ PselT,
        float* __restrict__ out) {
    __shared__ __align__(16) unsigned short lds[8192];

    const int t  = threadIdx.x;
    const int b  = blockIdx.z;
    const int s0 = blockIdx.y * 128;
    const int d0 = blockIdx.x * 128;
    const int w = t >> 6, l = t & 63;
    const int wm = w & 1, wn = w >> 1;
    const int lr = l & 15, quad = l >> 4;

    const int srow = t >> 2;
    const int koff = (t & 3) * 8;
    const size_t offA0 = ((size_t)(b * S_ + s0 + srow)) * KSEL_ + koff;
    const size_t offA1 = offA0 + (size_t)64 * KSEL_;
    const size_t offB0 = ((size_t)(b * D_ + d0 + srow)) * KSEL_ + koff;
    const size_t offB1 = offB0 + (size_t)64 * KSEL_;
    char* lb = (char*)lds + w * 1024;

    int ra[4], rg[4];
#pragma unroll
    for (int i = 0; i < 4; i++) {
        ra[i] = (wm * 64 + i * 16 + lr) * 32 + quad * 8;
        rg[i] = (wn * 64 + i * 16 + lr) * 32 + quad * 8;
    }

    f32x4 acc[4][4];
#pragma unroll
    for (int i = 0; i < 4; i++)
#pragma unroll
        for (int j = 0; j < 4; j++) acc[i][j] = (f32x4){0.f, 0.f, 0.f, 0.f};

    for (int k0 = 0; k0 < KSEL_; k0 += 32) {
        gl2lds16(selact + offA0 + k0, lb + 0);
        gl2lds16(selact + offA1 + k0, lb + 4096);
        gl2lds16(PselT  + offB0 + k0, lb + 8192);
        gl2lds16(PselT  + offB1 + k0, lb + 12288);
        __syncthreads();

        short8 af[4], bf[4];
#pragma unroll
        for (int i = 0; i < 4; i++) {
            af[i] = *(const short8*)(lds + ra[i]);
            bf[i] = *(const short8*)(lds + 4096 + rg[i]);
        }
#pragma unroll
        for (int mt = 0; mt < 4; mt++)
#pragma unroll
            for (int nt = 0; nt < 4; nt++)
                acc[mt][nt] = __builtin_amdgcn_mfma_f32_16x16x32_bf16(af[mt], bf[nt], acc[mt][nt], 0, 0, 0);
        __syncthreads();
    }

#pragma unroll
    for (int mt = 0; mt < 4; mt++)
#pragma unroll
        for (int nt = 0; nt < 4; nt++)
#pragma unroll
            for (int r = 0; r < 4; r++)
                out[((size_t)(b * S_ + s0 + wm * 64 + mt * 16 + quad * 4 + r)) * D_
                    + d0 + wn * 64 + nt * 16 + lr] = acc[mt][nt][r];
}

// ---------------------------------------------------------------------------
// Workspace layout (bytes):
//   Ahi/Alo/Ghi/Glo bf16  @ 0..67108863   (4 x 16,777,216)
//   scores fp32           @ 67,108,864    (65,536)
//   pidx   int            @ 67,174,400    (8,192)
//   selact bf16           @ 67,182,592    (8,388,608)
//   PselT  bf16           @ 75,571,200    (4,194,304)      -> 79,765,504 (base)
//   C      bf16 [8][2048][2048] @ 79,765,504 (67,108,864)  -> 146,874,368 (big)
// ---------------------------------------------------------------------------
extern "C" void kernel_launch(void* const* d_in, const int* in_sizes, int n_in,
                              void* d_out, int out_size, void* d_ws, size_t ws_size,
                              hipStream_t stream) {
    (void)in_sizes; (void)n_in; (void)out_size;
    const float* act  = (const float*)d_in[0];
    const int*   idx  = (const int*)d_in[1];
    const float* W    = (const float*)d_in[3];
    const float* proj = (const float*)d_in[4];
    float*       out  = (float*)d_out;

    char* ws = (char*)d_ws;
    unsigned short* Ahi    = (unsigned short*)(ws + 0);
    unsigned short* Alo    = (unsigned short*)(ws + 16777216);
    unsigned short* Ghi    = (unsigned short*)(ws + 33554432);
    unsigned short* Glo    = (unsigned short*)(ws + 50331648);
    float*          scores = (float*)(ws + 67108864);
    int*            pidx   = (int*)(ws + 67174400);
    unsigned short* selact = (unsigned short*)(ws + 67182592);
    unsigned short* PselT  = (unsigned short*)(ws + 75571200);
    unsigned short* Cbf    = (unsigned short*)(ws + 79765504);
    const bool big = ws_size >= 146874368ull;

    hipMemsetAsync(scores, 0, B_ * P_ * sizeof(float), stream);

    split_a_kernel<<<dim3(B_ * S_ * KIN_ / 1024), 256, 0, stream>>>(act, Ahi, Alo);
    gather_w_kernel<<<dim3(B_ * P_), 256, 0, stream>>>(W, idx, Ghi, Glo);

    if (big) {
        gemm1_score<true><<<dim3(P_ / 128, S_ / 128, B_), 256, 0, stream>>>(
            Ahi, Alo, Ghi, Glo, scores, Cbf);
        topk_kernel<<<dim3(B_), 1024, 0, stream>>>(scores, pidx);
        gather_act_kernel<<<dim3(S_ / 8, B_), 256, 0, stream>>>(Cbf, pidx, selact);
    } else {
        gemm1_score<false><<<dim3(P_ / 128, S_ / 128, B_), 256, 0, stream>>>(
            Ahi, Alo, Ghi, Glo, scores, nullptr);
        topk_kernel<<<dim3(B_), 1024, 0, stream>>>(scores, pidx);
        gemm1b_selact<<<dim3(KSEL_ / 128, S_ / 128, B_), 256, 0, stream>>>(
            Ahi, Alo, Ghi, Glo, pidx, selact);
    }
    gather_proj_t<<<dim3(D_ / 64, KSEL_ / 64, B_), 256, 0, stream>>>(proj, pidx, PselT);
    gemm2_mfma<<<dim3(D_ / 128, S_ / 128, B_), 256, 0, stream>>>(selact, PselT, out);
}

// Round 5
// 404.255 us; speedup vs baseline: 1.7133x; 1.0266x over previous
//
#include <hip/hip_runtime.h>
#include <hip/hip_bf16.h>
#include <math.h>

#define B_    8
#define S_    2048
#define KIN_  512
#define NIN_  4096
#define P_    2048
#define D_    1024
#define KSEL_ 256

typedef __attribute__((ext_vector_type(8))) short short8;
typedef __attribute__((ext_vector_type(4))) float f32x4;

__device__ __forceinline__ unsigned short f2bf(float f) {
    unsigned u = __float_as_uint(f);
    unsigned r = (u + 0x7fffu + ((u >> 16) & 1u)) >> 16;
    return (unsigned short)r;
}
__device__ __forceinline__ float bf2f(unsigned short h) {
    return __uint_as_float(((unsigned)h) << 16);
}
__device__ __forceinline__ float gelu_exact(float x) {
    return 0.5f * x * (1.0f + erff(x * 0.70710678118654752f));
}
__device__ __forceinline__ void gl2lds16(const void* g, void* l) {
    __builtin_amdgcn_global_load_lds(
        (const __attribute__((address_space(1))) unsigned int*)g,
        (__attribute__((address_space(3))) unsigned int*)l, 16, 0, 0);
}

// ---------------------------------------------------------------------------
// prep: blocks [0,8192): split A fp32 -> Ahi/Alo bf16 (float4 per thread)
//       blocks [8192,24576): gather W rows by idx, split to Ghi/Glo
// ---------------------------------------------------------------------------
__global__ __launch_bounds__(256) void prep_kernel(
        const float* __restrict__ A, const float* __restrict__ W,
        const int* __restrict__ idx,
        unsigned short* __restrict__ Ahi, unsigned short* __restrict__ Alo,
        unsigned short* __restrict__ Ghi, unsigned short* __restrict__ Glo) {
    int id = blockIdx.x;
    if (id < 8192) {
        size_t i = (size_t)id * 256 + threadIdx.x;   // float4 index
        float4 v = reinterpret_cast<const float4*>(A)[i];
        ushort4 hi, lo;
        hi.x = f2bf(v.x); lo.x = f2bf(v.x - bf2f(hi.x));
        hi.y = f2bf(v.y); lo.y = f2bf(v.y - bf2f(hi.y));
        hi.z = f2bf(v.z); lo.z = f2bf(v.z - bf2f(hi.z));
        hi.w = f2bf(v.w); lo.w = f2bf(v.w - bf2f(hi.w));
        reinterpret_cast<ushort4*>(Ahi)[i] = hi;
        reinterpret_cast<ushort4*>(Alo)[i] = lo;
    } else {
        int bp = id - 8192;             // 0 .. B*P-1
        int b  = bp >> 11;
        const int* ib = idx + (size_t)b * KIN_;
        const float* wrow = W + (size_t)(bp & 2047) * NIN_;
        size_t o = (size_t)bp * KIN_;
        for (int j = threadIdx.x; j < KIN_; j += 256) {
            float v = wrow[ib[j]];
            unsigned short h = f2bf(v);
            Ghi[o + j] = h;
            Glo[o + j] = f2bf(v - bf2f(h));
        }
    }
}

// ---------------------------------------------------------------------------
// gemm1_score: x = A*G^T (3-term split bf16 MFMA), scores += sum_s gelu(x).
// Optionally (STORE_C) writes bf16 gelu(x) to C [b][s][p].
// 128x128 tile, BK=32, dbuf LDS + raw vmcnt(8)/s_barrier pipeline.
// Block swizzle: 4x4 (p,s)-tile clusters pinned to one XCD (dispatch id % 8),
// so staging loads hit the per-XCD L2 (2 MB cluster working set < 4 MB).
// ---------------------------------------------------------------------------
template <bool STORE_C>
__global__ __launch_bounds__(256) void gemm1_score(
        const unsigned short* __restrict__ Ahi, const unsigned short* __restrict__ Alo,
        const unsigned short* __restrict__ Ghi, const unsigned short* __restrict__ Glo,
        float* __restrict__ scores, unsigned short* __restrict__ C) {
    __shared__ __align__(16) unsigned short lds[32768];  // 2 x 32KB buffers

    // --- XCD cluster swizzle: d -> (b, s0, p0) ---
    int d    = blockIdx.x;             // 0..2047
    int xcd  = d & 7;
    int slot = d >> 3;                 // 0..255
    int c    = (slot >> 4) * 8 + xcd;  // cluster 0..127, all 16 blocks same XCD
    int j    = slot & 15;              // position in 4x4 cluster
    int b    = c >> 4;
    int rc   = c & 15;
    int p0   = ((rc & 3) * 4 + (j & 3)) * 128;
    int s0   = ((rc >> 2) * 4 + (j >> 2)) * 128;

    const int t  = threadIdx.x;
    const int w = t >> 6, l = t & 63;
    const int wm = w & 1, wn = w >> 1;
    const int lr = l & 15, quad = l >> 4;

    const int srow = t >> 2;
    const int koff = (t & 3) * 8;
    const size_t baseA = ((size_t)(b * S_ + s0)) * KIN_;
    const size_t baseG = ((size_t)(b * P_ + p0)) * KIN_;
    const unsigned short* pA0 = Ahi + baseA + (size_t)srow * KIN_ + koff;
    const unsigned short* pA1 = pA0 + (size_t)64 * KIN_;
    const unsigned short* pL0 = Alo + baseA + (size_t)srow * KIN_ + koff;
    const unsigned short* pL1 = pL0 + (size_t)64 * KIN_;
    const unsigned short* pG0 = Ghi + baseG + (size_t)srow * KIN_ + koff;
    const unsigned short* pG1 = pG0 + (size_t)64 * KIN_;
    const unsigned short* pH0 = Glo + baseG + (size_t)srow * KIN_ + koff;
    const unsigned short* pH1 = pH0 + (size_t)64 * KIN_;
    char* lb = (char*)lds + w * 1024;

    int ra[4], rg[4];
#pragma unroll
    for (int i = 0; i < 4; i++) {
        ra[i] = (wm * 64 + i * 16 + lr) * 32 + quad * 8;
        rg[i] = (wn * 64 + i * 16 + lr) * 32 + quad * 8;
    }

    f32x4 acc[4][4];
#pragma unroll
    for (int i = 0; i < 4; i++)
#pragma unroll
        for (int jj = 0; jj < 4; jj++) acc[i][jj] = (f32x4){0.f, 0.f, 0.f, 0.f};

    auto issue = [&](int k0, int buf) {
        char* dst = lb + buf * 32768;
        gl2lds16(pA0 + k0, dst + 0);
        gl2lds16(pA1 + k0, dst + 4096);
        gl2lds16(pL0 + k0, dst + 8192);
        gl2lds16(pL1 + k0, dst + 12288);
        gl2lds16(pG0 + k0, dst + 16384);
        gl2lds16(pG1 + k0, dst + 20480);
        gl2lds16(pH0 + k0, dst + 24576);
        gl2lds16(pH1 + k0, dst + 28672);
    };

    issue(0, 0);
    for (int it = 0; it < KIN_ / 32; ++it) {
        if (it + 1 < KIN_ / 32) {
            issue((it + 1) * 32, (it + 1) & 1);
            asm volatile("s_waitcnt vmcnt(8)\n\ts_barrier" ::: "memory");
        } else {
            asm volatile("s_waitcnt vmcnt(0)\n\ts_barrier" ::: "memory");
        }
        const unsigned short* Lb = lds + (it & 1) * 16384;

        short8 gh[4], gl8[4];
#pragma unroll
        for (int i = 0; i < 4; i++) {
            gh[i]  = *(const short8*)(Lb + 8192 + rg[i]);
            gl8[i] = *(const short8*)(Lb + 12288 + rg[i]);
        }
#pragma unroll
        for (int mt = 0; mt < 4; mt++) {
            short8 ah = *(const short8*)(Lb + ra[mt]);
            short8 al = *(const short8*)(Lb + 4096 + ra[mt]);
#pragma unroll
            for (int nt = 0; nt < 4; nt++) {
                acc[mt][nt] = __builtin_amdgcn_mfma_f32_16x16x32_bf16(ah, gh[nt],  acc[mt][nt], 0, 0, 0);
                acc[mt][nt] = __builtin_amdgcn_mfma_f32_16x16x32_bf16(ah, gl8[nt], acc[mt][nt], 0, 0, 0);
                acc[mt][nt] = __builtin_amdgcn_mfma_f32_16x16x32_bf16(al, gh[nt],  acc[mt][nt], 0, 0, 0);
            }
        }
        asm volatile("s_barrier" ::: "memory");
    }

    // Epilogue: gelu, per-column score sums, optional bf16 C tile store
    float colsum[4] = {0.f, 0.f, 0.f, 0.f};
#pragma unroll
    for (int mt = 0; mt < 4; mt++)
#pragma unroll
        for (int nt = 0; nt < 4; nt++)
#pragma unroll
            for (int r = 0; r < 4; r++) {
                float g = gelu_exact(acc[mt][nt][r]);
                colsum[nt] += g;
                acc[mt][nt][r] = g;
            }
#pragma unroll
    for (int nt = 0; nt < 4; nt++) {
        colsum[nt] += __shfl_xor(colsum[nt], 16);
        colsum[nt] += __shfl_xor(colsum[nt], 32);
    }
    if (quad == 0) {
#pragma unroll
        for (int nt = 0; nt < 4; nt++)
            atomicAdd(&scores[b * P_ + p0 + wn * 64 + nt * 16 + lr], colsum[nt]);
    }

    if (STORE_C) {
#pragma unroll
        for (int mt = 0; mt < 4; mt++)
#pragma unroll
            for (int nt = 0; nt < 4; nt++)
#pragma unroll
                for (int r = 0; r < 4; r++) {
                    int row = wm * 64 + mt * 16 + quad * 4 + r;
                    int col = wn * 64 + nt * 16 + lr;
                    lds[row * 128 + col] = f2bf(acc[mt][nt][r]);
                }
        __syncthreads();
        for (int i = t; i < 2048; i += 256) {
            int row = i >> 4, ch = i & 15;
            uint4 v = *(const uint4*)(lds + row * 128 + ch * 8);
            *(uint4*)(C + ((size_t)(b * S_ + s0 + row)) * P_ + p0 + ch * 8) = v;
        }
    }
}

// ---------------------------------------------------------------------------
// top-256 of 2048 scores per batch (bitonic, desc, tie: low idx)
// ---------------------------------------------------------------------------
__global__ __launch_bounds__(1024) void topk_kernel(const float* __restrict__ scores,
                                                    int* __restrict__ pidx) {
    __shared__ float v[2048];
    __shared__ int   ix[2048];
    int b = blockIdx.x;
    int t = threadIdx.x;
    for (int i = t; i < 2048; i += 1024) { v[i] = scores[b * 2048 + i]; ix[i] = i; }
    __syncthreads();
    for (int k = 2; k <= 2048; k <<= 1) {
        for (int j = k >> 1; j > 0; j >>= 1) {
            for (int i = t; i < 2048; i += 1024) {
                int o = i ^ j;
                if (o > i) {
                    bool desc = ((i & k) == 0);
                    float va = v[i], vb = v[o];
                    int ia = ix[i], ib = ix[o];
                    bool b_first = (vb > va) || (vb == va && ib < ia);
                    if (desc == b_first) { v[i] = vb; v[o] = va; ix[i] = ib; ix[o] = ia; }
                }
            }
            __syncthreads();
        }
    }
    if (t < KSEL_) pidx[b * KSEL_ + t] = ix[t];
}

// ---------------------------------------------------------------------------
// gathers: blocks [0,2048): selact[b][s][t] = C[b][s][pidx[b][t]]
//          blocks [2048,2560): PselT[b][d][k] = bf16(proj[pidx[b][k]][d])
// ---------------------------------------------------------------------------
__global__ __launch_bounds__(256) void gathers_kernel(
        const unsigned short* __restrict__ C, const float* __restrict__ proj,
        const int* __restrict__ pidx,
        unsigned short* __restrict__ selact, unsigned short* __restrict__ PselT) {
    __shared__ int pj[256];
    __shared__ unsigned short tile[64][65];
    int id = blockIdx.x, t = threadIdx.x;
    if (id < 2048) {
        int b = id >> 8;
        pj[t] = pidx[b * KSEL_ + t];
        __syncthreads();
        size_t r0 = (size_t)b * S_ + (id & 255) * 8;
#pragma unroll
        for (int r = 0; r < 8; ++r) {
            size_t row = r0 + r;
            selact[row * KSEL_ + t] = C[row * P_ + pj[t]];
        }
    } else {
        int g = id - 2048;
        int d0 = (g & 15) * 64, k0 = ((g >> 4) & 3) * 64, b = g >> 6;
        int tr = t >> 6;     // 0..3
        int tc = t & 63;
#pragma unroll
        for (int r = 0; r < 16; r++) {
            int kk = r * 4 + tr;
            int prow = pidx[b * KSEL_ + k0 + kk];
            tile[kk][tc] = f2bf(proj[(size_t)prow * D_ + d0 + tc]);
        }
        __syncthreads();
#pragma unroll
        for (int r = 0; r < 16; r++) {
            int dd = r * 4 + tr;
            PselT[((size_t)(b * D_ + d0 + dd)) * KSEL_ + k0 + tc] = tile[tc][dd];
        }
    }
}

// ---------------------------------------------------------------------------
// gemm1b (fallback when ws too small): recompute selected 256 columns
// ---------------------------------------------------------------------------
__global__ __launch_bounds__(256) void gemm1b_selact(
        const unsigned short* __restrict__ Ahi, const unsigned short* __restrict__ Alo,
        const unsigned short* __restrict__ Ghi, const unsigned short* __restrict__ Glo,
        const int* __restrict__ pidx, unsigned short* __restrict__ selact) {
    __shared__ __align__(16) unsigned short lds[16384];

    const int t  = threadIdx.x;
    const int b  = blockIdx.z;
    const int s0 = blockIdx.y * 128;
    const int n0 = blockIdx.x * 128;
    const int w = t >> 6, l = t & 63;
    const int wm = w & 1, wn = w >> 1;
    const int lr = l & 15, quad = l >> 4;

    const int srow = t >> 2;
    const int koff = (t & 3) * 8;
    const size_t baseA = ((size_t)(b * S_ + s0)) * KIN_;
    const size_t offA0 = baseA + (size_t)srow * KIN_ + koff;
    const size_t offA1 = offA0 + (size_t)64 * KIN_;
    const int prow0 = pidx[b * KSEL_ + n0 + srow];
    const int prow1 = pidx[b * KSEL_ + n0 + 64 + srow];
    const size_t offG0 = ((size_t)(b * P_ + prow0)) * KIN_ + koff;
    const size_t offG1 = ((size_t)(b * P_ + prow1)) * KIN_ + koff;
    char* lb = (char*)lds + w * 1024;

    int ra[4], rg[4];
#pragma unroll
    for (int i = 0; i < 4; i++) {
        ra[i] = (wm * 64 + i * 16 + lr) * 32 + quad * 8;
        rg[i] = (wn * 64 + i * 16 + lr) * 32 + quad * 8;
    }

    f32x4 acc[4][4];
#pragma unroll
    for (int i = 0; i < 4; i++)
#pragma unroll
        for (int j = 0; j < 4; j++) acc[i][j] = (f32x4){0.f, 0.f, 0.f, 0.f};

    for (int k0 = 0; k0 < KIN_; k0 += 32) {
        gl2lds16(Ahi + offA0 + k0, lb + 0);
        gl2lds16(Ahi + offA1 + k0, lb + 4096);
        gl2lds16(Alo + offA0 + k0, lb + 8192);
        gl2lds16(Alo + offA1 + k0, lb + 12288);
        gl2lds16(Ghi + offG0 + k0, lb + 16384);
        gl2lds16(Ghi + offG1 + k0, lb + 20480);
        gl2lds16(Glo + offG0 + k0, lb + 24576);
        gl2lds16(Glo + offG1 + k0, lb + 28672);
        __syncthreads();

        short8 ah[4], al8[4], gh[4], gl8[4];
#pragma unroll
        for (int i = 0; i < 4; i++) {
            ah[i]  = *(const short8*)(lds + ra[i]);
            al8[i] = *(const short8*)(lds + 4096 + ra[i]);
            gh[i]  = *(const short8*)(lds + 8192 + rg[i]);
            gl8[i] = *(const short8*)(lds + 12288 + rg[i]);
        }
#pragma unroll
        for (int mt = 0; mt < 4; mt++)
#pragma unroll
            for (int nt = 0; nt < 4; nt++) {
                acc[mt][nt] = __builtin_amdgcn_mfma_f32_16x16x32_bf16(ah[mt],  gh[nt],  acc[mt][nt], 0, 0, 0);
                acc[mt][nt] = __builtin_amdgcn_mfma_f32_16x16x32_bf16(ah[mt],  gl8[nt], acc[mt][nt], 0, 0, 0);
                acc[mt][nt] = __builtin_amdgcn_mfma_f32_16x16x32_bf16(al8[mt], gh[nt],  acc[mt][nt], 0, 0, 0);
            }
        __syncthreads();
    }

#pragma unroll
    for (int mt = 0; mt < 4; mt++)
#pragma unroll
        for (int nt = 0; nt < 4; nt++)
#pragma unroll
            for (int r = 0; r < 4; r++) {
                int row = wm * 64 + mt * 16 + quad * 4 + r;
                int col = wn * 64 + nt * 16 + lr;
                lds[row * 128 + col] = f2bf(gelu_exact(acc[mt][nt][r]));
            }
    __syncthreads();
    for (int i = t; i < 2048; i += 256) {
        int row = i >> 4, ch = i & 15;
        uint4 v = *(const uint4*)(lds + row * 128 + ch * 8);
        *(uint4*)(selact + ((size_t)(b * S_ + s0 + row)) * KSEL_ + n0 + ch * 8) = v;
    }
}

// ---------------------------------------------------------------------------
// gemm2: out[b][s][d] = sum_k selact[b][s][k] * PselT[b][d][k]  (bf16 MFMA)
// dbuf LDS + raw vmcnt(4)/s_barrier pipeline.
// ---------------------------------------------------------------------------
__global__ __launch_bounds__(256) void gemm2_mfma(
        const unsigned short* __restrict__ selact,
        const unsigned short* __restrict__ PselT,
        float* __restrict__ out) {
    __shared__ __align__(16) unsigned short lds[16384];  // 2 x 16KB buffers

    const int t  = threadIdx.x;
    const int b  = blockIdx.z;
    const int s0 = blockIdx.y * 128;
    const int d0 = blockIdx.x * 128;
    const int w = t >> 6, l = t & 63;
    const int wm = w & 1, wn = w >> 1;
    const int lr = l & 15, quad = l >> 4;

    const int srow = t >> 2;
    const int koff = (t & 3) * 8;
    const unsigned short* pA0 = selact + ((size_t)(b * S_ + s0 + srow)) * KSEL_ + koff;
    const unsigned short* pA1 = pA0 + (size_t)64 * KSEL_;
    const unsigned short* pB0 = PselT + ((size_t)(b * D_ + d0 + srow)) * KSEL_ + koff;
    const unsigned short* pB1 = pB0 + (size_t)64 * KSEL_;
    char* lb = (char*)lds + w * 1024;

    int ra[4], rg[4];
#pragma unroll
    for (int i = 0; i < 4; i++) {
        ra[i] = (wm * 64 + i * 16 + lr) * 32 + quad * 8;
        rg[i] = (wn * 64 + i * 16 + lr) * 32 + quad * 8;
    }

    f32x4 acc[4][4];
#pragma unroll
    for (int i = 0; i < 4; i++)
#pragma unroll
        for (int j = 0; j < 4; j++) acc[i][j] = (f32x4){0.f, 0.f, 0.f, 0.f};

    auto issue = [&](int k0, int buf) {
        char* dst = lb + buf * 16384;
        gl2lds16(pA0 + k0, dst + 0);
        gl2lds16(pA1 + k0, dst + 4096);
        gl2lds16(pB0 + k0, dst + 8192);
        gl2lds16(pB1 + k0, dst + 12288);
    };

    issue(0, 0);
    for (int it = 0; it < KSEL_ / 32; ++it) {
        if (it + 1 < KSEL_ / 32) {
            issue((it + 1) * 32, (it + 1) & 1);
            asm volatile("s_waitcnt vmcnt(4)\n\ts_barrier" ::: "memory");
        } else {
            asm volatile("s_waitcnt vmcnt(0)\n\ts_barrier" ::: "memory");
        }
        const unsigned short* Lb = lds + (it & 1) * 8192;

        short8 af[4], bf[4];
#pragma unroll
        for (int i = 0; i < 4; i++) {
            af[i] = *(const short8*)(Lb + ra[i]);
            bf[i] = *(const short8*)(Lb + 4096 + rg[i]);
        }
#pragma unroll
        for (int mt = 0; mt < 4; mt++)
#pragma unroll
            for (int nt = 0; nt < 4; nt++)
                acc[mt][nt] = __builtin_amdgcn_mfma_f32_16x16x32_bf16(af[mt], bf[nt], acc[mt][nt], 0, 0, 0);
        asm volatile("s_barrier" ::: "memory");
    }

#pragma unroll
    for (int mt = 0; mt < 4; mt++)
#pragma unroll
        for (int nt = 0; nt < 4; nt++)
#pragma unroll
            for (int r = 0; r < 4; r++)
                out[((size_t)(b * S_ + s0 + wm * 64 + mt * 16 + quad * 4 + r)) * D_
                    + d0 + wn * 64 + nt * 16 + lr] = acc[mt][nt][r];
}

// ---------------------------------------------------------------------------
// Workspace layout (bytes):
//   Ahi/Alo/Ghi/Glo bf16  @ 0..67108863   (4 x 16,777,216)
//   scores fp32           @ 67,108,864    (65,536)
//   pidx   int            @ 67,174,400    (8,192)
//   selact bf16           @ 67,182,592    (8,388,608)
//   PselT  bf16           @ 75,571,200    (4,194,304)      -> 79,765,504 (base)
//   C      bf16 [8][2048][2048] @ 79,765,504 (67,108,864)  -> 146,874,368 (big)
// ---------------------------------------------------------------------------
extern "C" void kernel_launch(void* const* d_in, const int* in_sizes, int n_in,
                              void* d_out, int out_size, void* d_ws, size_t ws_size,
                              hipStream_t stream) {
    (void)in_sizes; (void)n_in; (void)out_size;
    const float* act  = (const float*)d_in[0];
    const int*   idx  = (const int*)d_in[1];
    const float* W    = (const float*)d_in[3];
    const float* proj = (const float*)d_in[4];
    float*       out  = (float*)d_out;

    char* ws = (char*)d_ws;
    unsigned short* Ahi    = (unsigned short*)(ws + 0);
    unsigned short* Alo    = (unsigned short*)(ws + 16777216);
    unsigned short* Ghi    = (unsigned short*)(ws + 33554432);
    unsigned short* Glo    = (unsigned short*)(ws + 50331648);
    float*          scores = (float*)(ws + 67108864);
    int*            pidx   = (int*)(ws + 67174400);
    unsigned short* selact = (unsigned short*)(ws + 67182592);
    unsigned short* PselT  = (unsigned short*)(ws + 75571200);
    unsigned short* Cbf    = (unsigned short*)(ws + 79765504);
    const bool big = ws_size >= 146874368ull;

    hipMemsetAsync(scores, 0, B_ * P_ * sizeof(float), stream);

    prep_kernel<<<dim3(8192 + B_ * P_), 256, 0, stream>>>(act, W, idx, Ahi, Alo, Ghi, Glo);

    if (big) {
        gemm1_score<true><<<dim3(2048), 256, 0, stream>>>(Ahi, Alo, Ghi, Glo, scores, Cbf);
        topk_kernel<<<dim3(B_), 1024, 0, stream>>>(scores, pidx);
        gathers_kernel<<<dim3(2048 + 512), 256, 0, stream>>>(Cbf, proj, pidx, selact, PselT);
    } else {
        gemm1_score<false><<<dim3(2048), 256, 0, stream>>>(Ahi, Alo, Ghi, Glo, scores, nullptr);
        topk_kernel<<<dim3(B_), 1024, 0, stream>>>(scores, pidx);
        gemm1b_selact<<<dim3(KSEL_ / 128, S_ / 128, B_), 256, 0, stream>>>(
            Ahi, Alo, Ghi, Glo, pidx, selact);
        gathers_kernel<<<dim3(2048 + 512), 256, 0, stream>>>(Cbf, proj, pidx, selact, PselT);
    }
    gemm2_mfma<<<dim3(D_ / 128, S_ / 128, B_), 256, 0, stream>>>(selact, PselT, out);
}